// Round 10
// baseline (646.098 us; speedup 1.0000x reference)
//
#include <hip/hip_runtime.h>
#include <hip/hip_bf16.h>
#include <cstdint>
#include <cstddef>

#define B_DIM 64
#define K_DIM 2048
#define D_DIM 32400
#define KTILE 128

typedef __bf16 bf16x8 __attribute__((ext_vector_type(8)));
typedef float f32x4 __attribute__((ext_vector_type(4)));

union U128 { uint4 u; bf16x8 b; };

__device__ inline bf16x8 asbf(uint4 u) { U128 x; x.u = u; return x.b; }

__device__ inline uint4 neg4(uint4 u) {
    u.x ^= 0x80008000u; u.y ^= 0x80008000u; u.z ^= 0x80008000u; u.w ^= 0x80008000u;
    return u;
}

__device__ inline f32x4 mfma16(bf16x8 a, bf16x8 b, f32x4 c) {
    return __builtin_amdgcn_mfma_f32_16x16x32_bf16(a, b, c, 0, 0, 0);
}

// guarded float4 load: element index d within row pointer p, limit dlim
__device__ inline f32x4 ld4g(const float* __restrict__ p, int d, int dlim) {
    f32x4 r;
    if (d + 4 <= dlim) {
        float4 v = *reinterpret_cast<const float4*>(p + d);
        r[0] = v.x; r[1] = v.y; r[2] = v.z; r[3] = v.w;
    } else {
        #pragma unroll
        for (int j = 0; j < 4; ++j) r[j] = (d + j < dlim) ? p[d + j] : 0.0f;
    }
    return r;
}

// guarded 8x bf16 (16B) load
__device__ inline uint4 ld8bf(const __bf16* __restrict__ p, int d, int dlim) {
    if (d + 8 <= dlim) return *reinterpret_cast<const uint4*>(p + d);
    union { uint4 u; __bf16 h[8]; } x;
    #pragma unroll
    for (int j = 0; j < 8; ++j) x.h[j] = (d + j < dlim) ? p[d + j] : (__bf16)0.0f;
    return x.u;
}

// pack two floats -> dword of 2 bf16 (lo = a, hi = b)
__device__ inline uint32_t pk(float a, float b) {
    union { __bf16 h[2]; uint32_t u; } x;
    x.h[0] = (__bf16)a; x.h[1] = (__bf16)b;
    return x.u;
}

// ---------------------------------------------------------------------------
// Phase 0: X f32 -> bf16
// ---------------------------------------------------------------------------
__global__ __launch_bounds__(256) void xbf_kernel(
    const float* __restrict__ Xre, const float* __restrict__ Xim,
    __bf16* __restrict__ XreB, __bf16* __restrict__ XimB)
{
    const int i = (blockIdx.x * 256 + threadIdx.x) * 4;
    if (i < B_DIM * D_DIM) {
        float4 a = *reinterpret_cast<const float4*>(Xre + i);
        float4 b = *reinterpret_cast<const float4*>(Xim + i);
        *(uint2*)(XreB + i) = make_uint2(pk(a.x, a.y), pk(a.z, a.w));
        *(uint2*)(XimB + i) = make_uint2(pk(b.x, b.y), pk(b.z, b.w));
    }
}

// ---------------------------------------------------------------------------
// Phase 1 v3: coeffs[b,k] = (sum_d X*conj(bases))*w[k], split-D atomic.
// r6 structure (KTILE=128, KS=64, 256B/instr staging, x=ktg grid) with the
// LDS pad replaced by a T2 XOR swizzle (byte ^= (row&7)<<4): no-pad tiles
// [64|128][64] bf16 = 49.2 KB -> 3 blocks/CU (was 55.3 KB -> 2). Fragment
// b128 reads become 2-way bank aliasing (free per m136).
// ---------------------------------------------------------------------------
// swizzled byte offset within a plane of row-stride 128B (64 bf16)
__device__ inline int swz128(int row, int delem) {
    return (row * 128 + delem * 2) ^ ((row & 7) << 4);
}

template <bool XBF>
__global__ __launch_bounds__(256, 3) void p1_coeffs(
    const float* __restrict__ XreF, const float* __restrict__ XimF,
    const __bf16* __restrict__ XreB, const __bf16* __restrict__ XimB,
    const float* __restrict__ Bre, const float* __restrict__ Bim,
    const float* __restrict__ Wre, const float* __restrict__ Wim,
    float* __restrict__ Cre, float* __restrict__ Cim)
{
    __shared__ __align__(16) __bf16 sX[2][64 * 64];     // [re/im], swizzled
    __shared__ __align__(16) __bf16 sB[2][KTILE * 64];  // [re/im], swizzled

    const int ktg = blockIdx.x;       // 16 k-groups of 128  (xcd = ktg%8)
    const int dc  = blockIdx.y;       // 32 d-chunks of 1024
    const int tid  = threadIdx.x;
    const int lane = tid & 63;
    const int w    = tid >> 6;
    const int r    = lane & 15;
    const int g    = lane >> 4;

    const int kbase  = ktg * KTILE;
    const int dstart = dc * 1024;
    const int dend   = min(dstart + 1024, D_DIM);
    const int nsteps = (dend - dstart + 63) >> 6;

    const int srow = tid >> 4;          // 0..15 (+16 per j)
    const int sd   = (tid & 15) * 4;    // f32 elems 0..60
    const int rowx = tid >> 3;          // 0..31 (+32 per j)
    const int colx = (tid & 7) * 8;     // bf16 elems 0..56

    f32x4 bst[16];
    uint4 xst[4];
    f32x4 xstf[8];

    auto LOADS = [&](int s) {
        const int dg = dstart + s * 64 + sd;
        #pragma unroll
        for (int j = 0; j < 8; ++j) {
            const int row = j * 16 + srow;
            bst[j]     = ld4g(Bre + (size_t)(kbase + row) * D_DIM, dg, dend);
            bst[8 + j] = ld4g(Bim + (size_t)(kbase + row) * D_DIM, dg, dend);
        }
        if (XBF) {
            const int dgx = dstart + s * 64 + colx;
            xst[0] = ld8bf(XreB + (size_t)rowx * D_DIM,        dgx, dend);
            xst[1] = ld8bf(XreB + (size_t)(rowx + 32) * D_DIM, dgx, dend);
            xst[2] = ld8bf(XimB + (size_t)rowx * D_DIM,        dgx, dend);
            xst[3] = ld8bf(XimB + (size_t)(rowx + 32) * D_DIM, dgx, dend);
        } else {
            #pragma unroll
            for (int j = 0; j < 4; ++j) {
                const int row = j * 16 + srow;
                xstf[j]     = ld4g(XreF + (size_t)row * D_DIM, dg, dend);
                xstf[4 + j] = ld4g(XimF + (size_t)row * D_DIM, dg, dend);
            }
        }
    };

    auto WRITE = [&]() {
        char* b0 = (char*)&sB[0][0];
        char* b1 = (char*)&sB[1][0];
        #pragma unroll
        for (int j = 0; j < 8; ++j) {
            const int row = j * 16 + srow;
            const int off = swz128(row, sd);
            *(uint2*)(b0 + off) = make_uint2(pk(bst[j][0],     bst[j][1]),     pk(bst[j][2],     bst[j][3]));
            *(uint2*)(b1 + off) = make_uint2(pk(bst[8 + j][0], bst[8 + j][1]), pk(bst[8 + j][2], bst[8 + j][3]));
        }
        char* x0 = (char*)&sX[0][0];
        char* x1 = (char*)&sX[1][0];
        if (XBF) {
            *(uint4*)(x0 + swz128(rowx, colx))      = xst[0];
            *(uint4*)(x0 + swz128(rowx + 32, colx)) = xst[1];
            *(uint4*)(x1 + swz128(rowx, colx))      = xst[2];
            *(uint4*)(x1 + swz128(rowx + 32, colx)) = xst[3];
        } else {
            #pragma unroll
            for (int j = 0; j < 4; ++j) {
                const int row = j * 16 + srow;
                const int off = swz128(row, sd);
                *(uint2*)(x0 + off) = make_uint2(pk(xstf[j][0],     xstf[j][1]),     pk(xstf[j][2],     xstf[j][3]));
                *(uint2*)(x1 + off) = make_uint2(pk(xstf[4 + j][0], xstf[4 + j][1]), pk(xstf[4 + j][2], xstf[4 + j][3]));
            }
        }
    };

    const int m0  = (w & 1) * 32;     // local b quadrant (32 rows)
    const int nl0 = (w >> 1) * 64;    // local k span (64 cols)

    f32x4 accRe[2][4] = {};
    f32x4 accIm[2][4] = {};

    auto COMPUTE = [&]() {
        const char* x0 = (const char*)&sX[0][0];
        const char* x1 = (const char*)&sX[1][0];
        const char* b0 = (const char*)&sB[0][0];
        const char* b1 = (const char*)&sB[1][0];
        #pragma unroll
        for (int kk = 0; kk < 2; ++kk) {
            const int dp = kk * 32 + g * 8;
            uint4 xre[2], xim[2], bre[4], bim[4];
            #pragma unroll
            for (int ms = 0; ms < 2; ++ms) {
                const int off = swz128(m0 + ms * 16 + r, dp);
                xre[ms] = *(const uint4*)(x0 + off);
                xim[ms] = *(const uint4*)(x1 + off);
            }
            #pragma unroll
            for (int ns = 0; ns < 4; ++ns) {
                const int off = swz128(nl0 + ns * 16 + r, dp);
                bre[ns] = *(const uint4*)(b0 + off);
                bim[ns] = *(const uint4*)(b1 + off);
            }
            #pragma unroll
            for (int ms = 0; ms < 2; ++ms)
            #pragma unroll
            for (int ns = 0; ns < 4; ++ns) {
                // C_re += Xre*Bre + Xim*Bim ; C_im += Xim*Bre - Xre*Bim
                accRe[ms][ns] = mfma16(asbf(xre[ms]), asbf(bre[ns]), accRe[ms][ns]);
                accRe[ms][ns] = mfma16(asbf(xim[ms]), asbf(bim[ns]), accRe[ms][ns]);
                accIm[ms][ns] = mfma16(asbf(xim[ms]), asbf(bre[ns]), accIm[ms][ns]);
                accIm[ms][ns] = mfma16(asbf(neg4(xre[ms])), asbf(bim[ns]), accIm[ms][ns]);
            }
        }
    };

    LOADS(0); WRITE(); __syncthreads();
    for (int s = 0; s < nsteps; ++s) {
        if (s + 1 < nsteps) LOADS(s + 1);
        COMPUTE();
        if (s + 1 < nsteps) {
            __syncthreads();   // all reads of the buffer done
            WRITE();           // overwrite with s+1 tile
            __syncthreads();   // writes visible
        }
    }

    // epilogue: scale by w[k], atomic accumulate (C/D: col=lane&15, row=g*4+i)
    #pragma unroll
    for (int ms = 0; ms < 2; ++ms)
    #pragma unroll
    for (int ns = 0; ns < 4; ++ns) {
        const int kb = kbase + nl0 + ns * 16 + r;
        const float wre = Wre[kb], wim = Wim[kb];
        #pragma unroll
        for (int i = 0; i < 4; ++i) {
            const int b = m0 + ms * 16 + g * 4 + i;
            const float cre = accRe[ms][ns][i];
            const float cim = accIm[ms][ns][i];
            atomicAdd(&Cre[b * K_DIM + kb], cre * wre - cim * wim);
            atomicAdd(&Cim[b * K_DIM + kb], cre * wim + cim * wre);
        }
    }
}

// ---------------------------------------------------------------------------
// Phase 1.5: coeffs f32 -> bf16
// ---------------------------------------------------------------------------
__global__ __launch_bounds__(256) void cbf_kernel(
    const float* __restrict__ Cre, const float* __restrict__ Cim,
    __bf16* __restrict__ CreBf, __bf16* __restrict__ CimBf)
{
    const int i = blockIdx.x * 256 + threadIdx.x;
    if (i < B_DIM * K_DIM) {
        CreBf[i] = (__bf16)Cre[i];
        CimBf[i] = (__bf16)Cim[i];
    }
}

// ---------------------------------------------------------------------------
// Phase 2 v3: out[b,d] += sum_{k in half} coeffs[b,k]*bases[k,d].
// r6 dataflow (f32 rows, 256B/instr staging, transposed [d][k] LDS tile,
// grid 507 x 2 k-halves, f32 atomicAdd into pre-zeroed out) but
// SINGLE-buffer LDS (18.4 KB) with the 2-barrier pattern -> VGPR-capped
// ~5 blocks/CU (was dbuf 36.9 KB -> 4).
// ---------------------------------------------------------------------------
#define P2_STRIDE 72  // 64 k + 8 pad (144B rows, 16B aligned)

template <bool WIM>
__global__ __launch_bounds__(256, 5) void p2_project(
    const float* __restrict__ Bre, const float* __restrict__ Bim,
    const __bf16* __restrict__ CreBf, const __bf16* __restrict__ CimBf,
    float* __restrict__ out)
{
    __shared__ __align__(16) __bf16 sT[2][64][P2_STRIDE];  // [mat][d][k]

    const int dt = blockIdx.x;
    const int kh = blockIdx.y;        // k half: 0 -> [0,1024), 1 -> [1024,2048)
    const int d0 = dt * 64;
    const int khbase = kh * (K_DIM / 2);
    const int tid  = threadIdx.x;
    const int lane = tid & 63;
    const int w    = tid >> 6;
    const int r    = lane & 15;
    const int g    = lane >> 4;

    // staging map: thread t handles k-rows 4*(t>>4)..+3 at d = (t&15)*4
    const int kq = tid >> 4;          // 0..15
    const int ds = (tid & 15) * 4;    // 0..60

    f32x4 st[8];  // 4 k-rows x {re, im}

    auto LOADS = [&](int t) {
        const int k0 = khbase + t * 64;
        #pragma unroll
        for (int j = 0; j < 4; ++j) {
            const size_t ro = (size_t)(k0 + kq * 4 + j) * D_DIM;
            st[j]     = ld4g(Bre + ro, d0 + ds, D_DIM);
            st[4 + j] = ld4g(Bim + ro, d0 + ds, D_DIM);
        }
    };

    auto WRITE = [&]() {
        #pragma unroll
        for (int i = 0; i < 4; ++i) {
            *(uint2*)&sT[0][ds + i][kq * 4] =
                make_uint2(pk(st[0][i], st[1][i]), pk(st[2][i], st[3][i]));
            *(uint2*)&sT[1][ds + i][kq * 4] =
                make_uint2(pk(st[4][i], st[5][i]), pk(st[6][i], st[7][i]));
        }
    };

    const int m0  = (w & 1) * 32;     // b quadrant
    const int nl0 = (w >> 1) * 32;    // local d quadrant

    f32x4 accRe[2][2] = {};
    f32x4 accIm[2][2] = {};

    auto COMPUTE = [&](int t) {
        const int k0 = khbase + t * 64;
        uint4 aRe[2][2], aIm[2][2];
        #pragma unroll
        for (int ms = 0; ms < 2; ++ms) {
            const size_t rowo = (size_t)(m0 + ms * 16 + r) * K_DIM;
            #pragma unroll
            for (int kk = 0; kk < 2; ++kk) {
                aRe[ms][kk] = *(const uint4*)&CreBf[rowo + k0 + kk * 32 + g * 8];
                aIm[ms][kk] = *(const uint4*)&CimBf[rowo + k0 + kk * 32 + g * 8];
            }
        }
        #pragma unroll
        for (int kk = 0; kk < 2; ++kk) {
            uint4 bre[2], bim[2];
            #pragma unroll
            for (int ns = 0; ns < 2; ++ns) {
                bre[ns] = *(const uint4*)&sT[0][nl0 + ns * 16 + r][kk * 32 + g * 8];
                bim[ns] = *(const uint4*)&sT[1][nl0 + ns * 16 + r][kk * 32 + g * 8];
            }
            #pragma unroll
            for (int ms = 0; ms < 2; ++ms)
            #pragma unroll
            for (int ns = 0; ns < 2; ++ns) {
                // out_re += cre*Bre - cim*Bim ; out_im += cre*Bim + cim*Bre
                accRe[ms][ns] = mfma16(asbf(aRe[ms][kk]), asbf(bre[ns]), accRe[ms][ns]);
                accRe[ms][ns] = mfma16(asbf(neg4(aIm[ms][kk])), asbf(bim[ns]), accRe[ms][ns]);
                if (WIM) {
                    accIm[ms][ns] = mfma16(asbf(aRe[ms][kk]), asbf(bim[ns]), accIm[ms][ns]);
                    accIm[ms][ns] = mfma16(asbf(aIm[ms][kk]), asbf(bre[ns]), accIm[ms][ns]);
                }
            }
        }
    };

    const int NT = (K_DIM / 2) / 64;  // 16
    LOADS(0); WRITE(); __syncthreads();
    for (int t = 0; t < NT; ++t) {
        if (t + 1 < NT) LOADS(t + 1);
        COMPUTE(t);
        if (t + 1 < NT) {
            __syncthreads();   // all reads of the tile done
            WRITE();           // overwrite with t+1 tile
            __syncthreads();   // writes visible
        }
    }

    #pragma unroll
    for (int ms = 0; ms < 2; ++ms)
    #pragma unroll
    for (int ns = 0; ns < 2; ++ns) {
        const int d = d0 + nl0 + ns * 16 + r;
        if (d < D_DIM) {
            #pragma unroll
            for (int i = 0; i < 4; ++i) {
                const int b = m0 + ms * 16 + g * 4 + i;
                if (!WIM) {
                    atomicAdd(&out[(size_t)b * D_DIM + d], accRe[ms][ns][i]);
                } else {
                    atomicAdd(&out[((size_t)b * D_DIM + d) * 2],     accRe[ms][ns][i]);
                    atomicAdd(&out[((size_t)b * D_DIM + d) * 2 + 1], accIm[ms][ns][i]);
                }
            }
        }
    }
}

extern "C" void kernel_launch(void* const* d_in, const int* in_sizes, int n_in,
                              void* d_out, int out_size, void* d_ws, size_t ws_size,
                              hipStream_t stream) {
    const float* Xre = (const float*)d_in[0];
    const float* Xim = (const float*)d_in[1];
    const float* Bre = (const float*)d_in[2];
    const float* Bim = (const float*)d_in[3];
    const float* Wre = (const float*)d_in[4];
    const float* Wim = (const float*)d_in[5];

    float*  Cre   = (float*)d_ws;                          // 512 KB
    float*  Cim   = Cre + B_DIM * K_DIM;                   // 512 KB
    __bf16* CreBf = (__bf16*)(Cim + B_DIM * K_DIM);        // 256 KB
    __bf16* CimBf = CreBf + B_DIM * K_DIM;                 // 256 KB
    __bf16* XreB  = CimBf + B_DIM * K_DIM;                 // 4.15 MB
    __bf16* XimB  = XreB + (size_t)B_DIM * D_DIM;          // 4.15 MB

    const size_t need = (size_t)2 * B_DIM * K_DIM * sizeof(float)
                      + (size_t)2 * B_DIM * K_DIM * sizeof(__bf16)
                      + (size_t)2 * B_DIM * D_DIM * sizeof(__bf16);
    const bool xbf = ws_size >= need;

    (void)hipMemsetAsync(d_ws, 0, (size_t)2 * B_DIM * K_DIM * sizeof(float), stream);
    (void)hipMemsetAsync(d_out, 0, (size_t)out_size * sizeof(float), stream);

    dim3 g1(K_DIM / KTILE, 32);  // x = k-group (drives XCD assignment), y = d-chunk
    if (xbf) {
        xbf_kernel<<<(B_DIM * D_DIM / 4 + 255) / 256, 256, 0, stream>>>(Xre, Xim, XreB, XimB);
        p1_coeffs<true><<<g1, 256, 0, stream>>>(Xre, Xim, XreB, XimB, Bre, Bim, Wre, Wim, Cre, Cim);
    } else {
        p1_coeffs<false><<<g1, 256, 0, stream>>>(Xre, Xim, XreB, XimB, Bre, Bim, Wre, Wim, Cre, Cim);
    }

    cbf_kernel<<<(B_DIM * K_DIM + 255) / 256, 256, 0, stream>>>(Cre, Cim, CreBf, CimBf);

    const int ndt = (D_DIM + 63) / 64;  // 507
    dim3 g2(ndt, 2);
    if (out_size == 2 * B_DIM * D_DIM) {
        p2_project<true><<<g2, 256, 0, stream>>>(Bre, Bim, CreBf, CimBf, (float*)d_out);
    } else {
        p2_project<false><<<g2, 256, 0, stream>>>(Bre, Bim, CreBf, CimBf, (float*)d_out);
    }
}

// Round 11
// 304.464 us; speedup vs baseline: 2.1221x; 2.1221x over previous
//
#include <hip/hip_runtime.h>
#include <hip/hip_bf16.h>
#include <cstdint>
#include <cstddef>

#define B_DIM 64
#define K_DIM 2048
#define D_DIM 32400
#define KTILE 128

typedef __bf16 bf16x8 __attribute__((ext_vector_type(8)));
typedef float f32x4 __attribute__((ext_vector_type(4)));

union U128 { uint4 u; bf16x8 b; };

__device__ inline bf16x8 asbf(uint4 u) { U128 x; x.u = u; return x.b; }

__device__ inline uint4 neg4(uint4 u) {
    u.x ^= 0x80008000u; u.y ^= 0x80008000u; u.z ^= 0x80008000u; u.w ^= 0x80008000u;
    return u;
}

__device__ inline f32x4 mfma16(bf16x8 a, bf16x8 b, f32x4 c) {
    return __builtin_amdgcn_mfma_f32_16x16x32_bf16(a, b, c, 0, 0, 0);
}

// guarded float4 load: element index d within row pointer p, limit dlim
__device__ inline f32x4 ld4g(const float* __restrict__ p, int d, int dlim) {
    f32x4 r;
    if (d + 4 <= dlim) {
        float4 v = *reinterpret_cast<const float4*>(p + d);
        r[0] = v.x; r[1] = v.y; r[2] = v.z; r[3] = v.w;
    } else {
        #pragma unroll
        for (int j = 0; j < 4; ++j) r[j] = (d + j < dlim) ? p[d + j] : 0.0f;
    }
    return r;
}

// guarded 8x bf16 (16B) load
__device__ inline uint4 ld8bf(const __bf16* __restrict__ p, int d, int dlim) {
    if (d + 8 <= dlim) return *reinterpret_cast<const uint4*>(p + d);
    union { uint4 u; __bf16 h[8]; } x;
    #pragma unroll
    for (int j = 0; j < 8; ++j) x.h[j] = (d + j < dlim) ? p[d + j] : (__bf16)0.0f;
    return x.u;
}

// pack two floats -> dword of 2 bf16 (lo = a, hi = b)
__device__ inline uint32_t pk(float a, float b) {
    union { __bf16 h[2]; uint32_t u; } x;
    x.h[0] = (__bf16)a; x.h[1] = (__bf16)b;
    return x.u;
}

// ---------------------------------------------------------------------------
// Phase 0: X f32 -> bf16
// ---------------------------------------------------------------------------
__global__ __launch_bounds__(256) void xbf_kernel(
    const float* __restrict__ Xre, const float* __restrict__ Xim,
    __bf16* __restrict__ XreB, __bf16* __restrict__ XimB)
{
    const int i = (blockIdx.x * 256 + threadIdx.x) * 4;
    if (i < B_DIM * D_DIM) {
        float4 a = *reinterpret_cast<const float4*>(Xre + i);
        float4 b = *reinterpret_cast<const float4*>(Xim + i);
        *(uint2*)(XreB + i) = make_uint2(pk(a.x, a.y), pk(a.z, a.w));
        *(uint2*)(XimB + i) = make_uint2(pk(b.x, b.y), pk(b.z, b.w));
    }
}

// ---------------------------------------------------------------------------
// Phase 1 (r6, empirical best): coeffs[b,k] = (sum_d X*conj(bases))*w[k].
// k-tile 128; KS=64; bases staged at 256B/instruction; X staged from bf16.
// Single-buffer LDS 55KB -> 2 blocks/CU. Grid x=ktg (xcd=ktg%8).
// NOTE: r7-r10 variants (global-X fragments, 512B staging, fused BT
// producer, XOR-swizzle + launch_bounds(,3)) ALL regressed — gather
// granularity, occupancy loss, prefetch serialization, scratch spill.
// ---------------------------------------------------------------------------
#define P1_STRIDE 72  // 64 d + 8 pad

template <bool XBF>
__global__ __launch_bounds__(256, 2) void p1_coeffs(
    const float* __restrict__ XreF, const float* __restrict__ XimF,
    const __bf16* __restrict__ XreB, const __bf16* __restrict__ XimB,
    const float* __restrict__ Bre, const float* __restrict__ Bim,
    const float* __restrict__ Wre, const float* __restrict__ Wim,
    float* __restrict__ Cre, float* __restrict__ Cim)
{
    __shared__ __align__(16) __bf16 sX[2][64][P1_STRIDE];     // [re/im][b][d]
    __shared__ __align__(16) __bf16 sB[2][KTILE][P1_STRIDE];  // [re/im][k][d]

    const int ktg = blockIdx.x;       // 16 k-groups of 128  (xcd = ktg%8)
    const int dc  = blockIdx.y;       // 32 d-chunks of 1024
    const int tid  = threadIdx.x;
    const int lane = tid & 63;
    const int w    = tid >> 6;
    const int r    = lane & 15;
    const int g    = lane >> 4;

    const int kbase  = ktg * KTILE;
    const int dstart = dc * 1024;
    const int dend   = min(dstart + 1024, D_DIM);
    const int nsteps = (dend - dstart + 63) >> 6;

    const int srow = tid >> 4;          // 0..15 (+16 per j)
    const int sd   = (tid & 15) * 4;    // f32 elems 0..60
    const int rowx = tid >> 3;          // 0..31 (+32 per j)
    const int colx = (tid & 7) * 8;     // bf16 elems 0..56

    f32x4 bst[16];
    uint4 xst[4];
    f32x4 xstf[8];

    auto LOADS = [&](int s) {
        const int dg = dstart + s * 64 + sd;
        #pragma unroll
        for (int j = 0; j < 8; ++j) {
            const int row = j * 16 + srow;
            bst[j]     = ld4g(Bre + (size_t)(kbase + row) * D_DIM, dg, dend);
            bst[8 + j] = ld4g(Bim + (size_t)(kbase + row) * D_DIM, dg, dend);
        }
        if (XBF) {
            const int dgx = dstart + s * 64 + colx;
            xst[0] = ld8bf(XreB + (size_t)rowx * D_DIM,        dgx, dend);
            xst[1] = ld8bf(XreB + (size_t)(rowx + 32) * D_DIM, dgx, dend);
            xst[2] = ld8bf(XimB + (size_t)rowx * D_DIM,        dgx, dend);
            xst[3] = ld8bf(XimB + (size_t)(rowx + 32) * D_DIM, dgx, dend);
        } else {
            #pragma unroll
            for (int j = 0; j < 4; ++j) {
                const int row = j * 16 + srow;
                xstf[j]     = ld4g(XreF + (size_t)row * D_DIM, dg, dend);
                xstf[4 + j] = ld4g(XimF + (size_t)row * D_DIM, dg, dend);
            }
        }
    };

    auto WRITE = [&]() {
        #pragma unroll
        for (int j = 0; j < 8; ++j) {
            const int row = j * 16 + srow;
            *(uint2*)&sB[0][row][sd] = make_uint2(pk(bst[j][0],     bst[j][1]),     pk(bst[j][2],     bst[j][3]));
            *(uint2*)&sB[1][row][sd] = make_uint2(pk(bst[8 + j][0], bst[8 + j][1]), pk(bst[8 + j][2], bst[8 + j][3]));
        }
        if (XBF) {
            *(uint4*)&sX[0][rowx][colx]      = xst[0];
            *(uint4*)&sX[0][rowx + 32][colx] = xst[1];
            *(uint4*)&sX[1][rowx][colx]      = xst[2];
            *(uint4*)&sX[1][rowx + 32][colx] = xst[3];
        } else {
            #pragma unroll
            for (int j = 0; j < 4; ++j) {
                const int row = j * 16 + srow;
                *(uint2*)&sX[0][row][sd] = make_uint2(pk(xstf[j][0],     xstf[j][1]),     pk(xstf[j][2],     xstf[j][3]));
                *(uint2*)&sX[1][row][sd] = make_uint2(pk(xstf[4 + j][0], xstf[4 + j][1]), pk(xstf[4 + j][2], xstf[4 + j][3]));
            }
        }
    };

    const int m0  = (w & 1) * 32;     // local b quadrant (32 rows)
    const int nl0 = (w >> 1) * 64;    // local k span (64 cols)

    f32x4 accRe[2][4] = {};
    f32x4 accIm[2][4] = {};

    auto COMPUTE = [&]() {
        #pragma unroll
        for (int kk = 0; kk < 2; ++kk) {
            const int dp = kk * 32 + g * 8;
            uint4 xre[2], xim[2], bre[4], bim[4];
            #pragma unroll
            for (int ms = 0; ms < 2; ++ms) {
                xre[ms] = *(const uint4*)&sX[0][m0 + ms * 16 + r][dp];
                xim[ms] = *(const uint4*)&sX[1][m0 + ms * 16 + r][dp];
            }
            #pragma unroll
            for (int ns = 0; ns < 4; ++ns) {
                bre[ns] = *(const uint4*)&sB[0][nl0 + ns * 16 + r][dp];
                bim[ns] = *(const uint4*)&sB[1][nl0 + ns * 16 + r][dp];
            }
            #pragma unroll
            for (int ms = 0; ms < 2; ++ms)
            #pragma unroll
            for (int ns = 0; ns < 4; ++ns) {
                // C_re += Xre*Bre + Xim*Bim ; C_im += Xim*Bre - Xre*Bim
                accRe[ms][ns] = mfma16(asbf(xre[ms]), asbf(bre[ns]), accRe[ms][ns]);
                accRe[ms][ns] = mfma16(asbf(xim[ms]), asbf(bim[ns]), accRe[ms][ns]);
                accIm[ms][ns] = mfma16(asbf(xim[ms]), asbf(bre[ns]), accIm[ms][ns]);
                accIm[ms][ns] = mfma16(asbf(neg4(xre[ms])), asbf(bim[ns]), accIm[ms][ns]);
            }
        }
    };

    LOADS(0); WRITE(); __syncthreads();
    for (int s = 0; s < nsteps; ++s) {
        if (s + 1 < nsteps) LOADS(s + 1);
        COMPUTE();
        if (s + 1 < nsteps) {
            __syncthreads();   // all reads of the buffer done
            WRITE();           // overwrite with s+1 tile
            __syncthreads();   // writes visible
        }
    }

    // epilogue: scale by w[k], atomic accumulate (C/D: col=lane&15, row=g*4+i)
    #pragma unroll
    for (int ms = 0; ms < 2; ++ms)
    #pragma unroll
    for (int ns = 0; ns < 4; ++ns) {
        const int kb = kbase + nl0 + ns * 16 + r;
        const float wre = Wre[kb], wim = Wim[kb];
        #pragma unroll
        for (int i = 0; i < 4; ++i) {
            const int b = m0 + ms * 16 + g * 4 + i;
            const float cre = accRe[ms][ns][i];
            const float cim = accIm[ms][ns][i];
            atomicAdd(&Cre[b * K_DIM + kb], cre * wre - cim * wim);
            atomicAdd(&Cim[b * K_DIM + kb], cre * wim + cim * wre);
        }
    }
}

// ---------------------------------------------------------------------------
// Phase 1.5: coeffs f32 -> bf16
// ---------------------------------------------------------------------------
__global__ __launch_bounds__(256) void cbf_kernel(
    const float* __restrict__ Cre, const float* __restrict__ Cim,
    __bf16* __restrict__ CreBf, __bf16* __restrict__ CimBf)
{
    const int i = blockIdx.x * 256 + threadIdx.x;
    if (i < B_DIM * K_DIM) {
        CreBf[i] = (__bf16)Cre[i];
        CimBf[i] = (__bf16)Cim[i];
    }
}

// ---------------------------------------------------------------------------
// Phase 2 (r6, empirical best): out[b,d] += sum_{k in half} coeffs*bases.
// K split in 2 halves (grid.y); f32 atomicAdd into pre-zeroed out.
// bases tile [64 k][64 d] staged TRANSPOSED into LDS [d][k]; 36.9 KB dbuf.
// ---------------------------------------------------------------------------
#define P2_STRIDE 72  // 64 k + 8 pad (144B rows, 16B aligned)

template <bool WIM>
__global__ __launch_bounds__(256) void p2_project(
    const float* __restrict__ Bre, const float* __restrict__ Bim,
    const __bf16* __restrict__ CreBf, const __bf16* __restrict__ CimBf,
    float* __restrict__ out)
{
    __shared__ __align__(16) __bf16 sT[2][2][64][P2_STRIDE];  // [buf][mat][d][k]

    const int dt = blockIdx.x;
    const int kh = blockIdx.y;        // k half: 0 -> [0,1024), 1 -> [1024,2048)
    const int d0 = dt * 64;
    const int khbase = kh * (K_DIM / 2);
    const int tid  = threadIdx.x;
    const int lane = tid & 63;
    const int w    = tid >> 6;
    const int r    = lane & 15;
    const int g    = lane >> 4;

    // staging map: thread t handles k-rows 4*(t>>4)..+3 at d = (t&15)*4
    const int kq = tid >> 4;          // 0..15
    const int ds = (tid & 15) * 4;    // 0..60

    f32x4 st[8];  // 4 k-rows x {re, im}

    auto LOADS = [&](int t) {
        const int k0 = khbase + t * 64;
        #pragma unroll
        for (int j = 0; j < 4; ++j) {
            const size_t ro = (size_t)(k0 + kq * 4 + j) * D_DIM;
            st[j]     = ld4g(Bre + ro, d0 + ds, D_DIM);
            st[4 + j] = ld4g(Bim + ro, d0 + ds, D_DIM);
        }
    };

    auto WRITE = [&](int buf) {
        #pragma unroll
        for (int i = 0; i < 4; ++i) {
            *(uint2*)&sT[buf][0][ds + i][kq * 4] =
                make_uint2(pk(st[0][i], st[1][i]), pk(st[2][i], st[3][i]));
            *(uint2*)&sT[buf][1][ds + i][kq * 4] =
                make_uint2(pk(st[4][i], st[5][i]), pk(st[6][i], st[7][i]));
        }
    };

    const int m0  = (w & 1) * 32;     // b quadrant
    const int nl0 = (w >> 1) * 32;    // local d quadrant

    f32x4 accRe[2][2] = {};
    f32x4 accIm[2][2] = {};

    auto COMPUTE = [&](int t, int buf) {
        const int k0 = khbase + t * 64;
        uint4 aRe[2][2], aIm[2][2];
        #pragma unroll
        for (int ms = 0; ms < 2; ++ms) {
            const size_t rowo = (size_t)(m0 + ms * 16 + r) * K_DIM;
            #pragma unroll
            for (int kk = 0; kk < 2; ++kk) {
                aRe[ms][kk] = *(const uint4*)&CreBf[rowo + k0 + kk * 32 + g * 8];
                aIm[ms][kk] = *(const uint4*)&CimBf[rowo + k0 + kk * 32 + g * 8];
            }
        }
        #pragma unroll
        for (int kk = 0; kk < 2; ++kk) {
            uint4 bre[2], bim[2];
            #pragma unroll
            for (int ns = 0; ns < 2; ++ns) {
                bre[ns] = *(const uint4*)&sT[buf][0][nl0 + ns * 16 + r][kk * 32 + g * 8];
                bim[ns] = *(const uint4*)&sT[buf][1][nl0 + ns * 16 + r][kk * 32 + g * 8];
            }
            #pragma unroll
            for (int ms = 0; ms < 2; ++ms)
            #pragma unroll
            for (int ns = 0; ns < 2; ++ns) {
                // out_re += cre*Bre - cim*Bim ; out_im += cre*Bim + cim*Bre
                accRe[ms][ns] = mfma16(asbf(aRe[ms][kk]), asbf(bre[ns]), accRe[ms][ns]);
                accRe[ms][ns] = mfma16(asbf(neg4(aIm[ms][kk])), asbf(bim[ns]), accRe[ms][ns]);
                if (WIM) {
                    accIm[ms][ns] = mfma16(asbf(aRe[ms][kk]), asbf(bim[ns]), accIm[ms][ns]);
                    accIm[ms][ns] = mfma16(asbf(aIm[ms][kk]), asbf(bre[ns]), accIm[ms][ns]);
                }
            }
        }
    };

    const int NT = (K_DIM / 2) / 64;  // 16
    LOADS(0); WRITE(0); __syncthreads();
    for (int t = 0; t < NT; ++t) {
        if (t + 1 < NT) LOADS(t + 1);
        COMPUTE(t, t & 1);
        if (t + 1 < NT) WRITE((t + 1) & 1);
        __syncthreads();
    }

    #pragma unroll
    for (int ms = 0; ms < 2; ++ms)
    #pragma unroll
    for (int ns = 0; ns < 2; ++ns) {
        const int d = d0 + nl0 + ns * 16 + r;
        if (d < D_DIM) {
            #pragma unroll
            for (int i = 0; i < 4; ++i) {
                const int b = m0 + ms * 16 + g * 4 + i;
                if (!WIM) {
                    atomicAdd(&out[(size_t)b * D_DIM + d], accRe[ms][ns][i]);
                } else {
                    atomicAdd(&out[((size_t)b * D_DIM + d) * 2],     accRe[ms][ns][i]);
                    atomicAdd(&out[((size_t)b * D_DIM + d) * 2 + 1], accIm[ms][ns][i]);
                }
            }
        }
    }
}

extern "C" void kernel_launch(void* const* d_in, const int* in_sizes, int n_in,
                              void* d_out, int out_size, void* d_ws, size_t ws_size,
                              hipStream_t stream) {
    const float* Xre = (const float*)d_in[0];
    const float* Xim = (const float*)d_in[1];
    const float* Bre = (const float*)d_in[2];
    const float* Bim = (const float*)d_in[3];
    const float* Wre = (const float*)d_in[4];
    const float* Wim = (const float*)d_in[5];

    float*  Cre   = (float*)d_ws;                          // 512 KB
    float*  Cim   = Cre + B_DIM * K_DIM;                   // 512 KB
    __bf16* CreBf = (__bf16*)(Cim + B_DIM * K_DIM);        // 256 KB
    __bf16* CimBf = CreBf + B_DIM * K_DIM;                 // 256 KB
    __bf16* XreB  = CimBf + B_DIM * K_DIM;                 // 4.15 MB
    __bf16* XimB  = XreB + (size_t)B_DIM * D_DIM;          // 4.15 MB

    const size_t need = (size_t)2 * B_DIM * K_DIM * sizeof(float)
                      + (size_t)2 * B_DIM * K_DIM * sizeof(__bf16)
                      + (size_t)2 * B_DIM * D_DIM * sizeof(__bf16);
    const bool xbf = ws_size >= need;

    (void)hipMemsetAsync(d_ws, 0, (size_t)2 * B_DIM * K_DIM * sizeof(float), stream);
    (void)hipMemsetAsync(d_out, 0, (size_t)out_size * sizeof(float), stream);

    dim3 g1(K_DIM / KTILE, 32);  // x = k-group (drives XCD assignment), y = d-chunk
    if (xbf) {
        xbf_kernel<<<(B_DIM * D_DIM / 4 + 255) / 256, 256, 0, stream>>>(Xre, Xim, XreB, XimB);
        p1_coeffs<true><<<g1, 256, 0, stream>>>(Xre, Xim, XreB, XimB, Bre, Bim, Wre, Wim, Cre, Cim);
    } else {
        p1_coeffs<false><<<g1, 256, 0, stream>>>(Xre, Xim, XreB, XimB, Bre, Bim, Wre, Wim, Cre, Cim);
    }

    cbf_kernel<<<(B_DIM * K_DIM + 255) / 256, 256, 0, stream>>>(Cre, Cim, CreBf, CimBf);

    const int ndt = (D_DIM + 63) / 64;  // 507
    dim3 g2(ndt, 2);
    if (out_size == 2 * B_DIM * D_DIM) {
        p2_project<true><<<g2, 256, 0, stream>>>(Bre, Bim, CreBf, CimBf, (float*)d_out);
    } else {
        p2_project<false><<<g2, 256, 0, stream>>>(Bre, Bim, CreBf, CimBf, (float*)d_out);
    }
}

// Round 12
// 290.998 us; speedup vs baseline: 2.2203x; 1.0463x over previous
//
#include <hip/hip_runtime.h>
#include <hip/hip_bf16.h>
#include <cstdint>
#include <cstddef>

#define B_DIM 64
#define K_DIM 2048
#define D_DIM 32400
#define KTILE 128
#define NDT   507   // number of 64-wide d-tiles (507*64 = 32448 >= 32400)

typedef __bf16 bf16x8 __attribute__((ext_vector_type(8)));
typedef float f32x4 __attribute__((ext_vector_type(4)));

union U128 { uint4 u; bf16x8 b; };

__device__ inline bf16x8 asbf(uint4 u) { U128 x; x.u = u; return x.b; }

__device__ inline uint4 neg4(uint4 u) {
    u.x ^= 0x80008000u; u.y ^= 0x80008000u; u.z ^= 0x80008000u; u.w ^= 0x80008000u;
    return u;
}

__device__ inline f32x4 mfma16(bf16x8 a, bf16x8 b, f32x4 c) {
    return __builtin_amdgcn_mfma_f32_16x16x32_bf16(a, b, c, 0, 0, 0);
}

// guarded float4 load: element index d within row pointer p, limit dlim
__device__ inline f32x4 ld4g(const float* __restrict__ p, int d, int dlim) {
    f32x4 r;
    if (d + 4 <= dlim) {
        float4 v = *reinterpret_cast<const float4*>(p + d);
        r[0] = v.x; r[1] = v.y; r[2] = v.z; r[3] = v.w;
    } else {
        #pragma unroll
        for (int j = 0; j < 4; ++j) r[j] = (d + j < dlim) ? p[d + j] : 0.0f;
    }
    return r;
}

// guarded 8x bf16 (16B) load
__device__ inline uint4 ld8bf(const __bf16* __restrict__ p, int d, int dlim) {
    if (d + 8 <= dlim) return *reinterpret_cast<const uint4*>(p + d);
    union { uint4 u; __bf16 h[8]; } x;
    #pragma unroll
    for (int j = 0; j < 8; ++j) x.h[j] = (d + j < dlim) ? p[d + j] : (__bf16)0.0f;
    return x.u;
}

// pack two floats -> dword of 2 bf16 (lo = a, hi = b)
__device__ inline uint32_t pk(float a, float b) {
    union { __bf16 h[2]; uint32_t u; } x;
    x.h[0] = (__bf16)a; x.h[1] = (__bf16)b;
    return x.u;
}

// ---------------------------------------------------------------------------
// Phase 0: X f32 -> bf16
// ---------------------------------------------------------------------------
__global__ __launch_bounds__(256) void xbf_kernel(
    const float* __restrict__ Xre, const float* __restrict__ Xim,
    __bf16* __restrict__ XreB, __bf16* __restrict__ XimB)
{
    const int i = (blockIdx.x * 256 + threadIdx.x) * 4;
    if (i < B_DIM * D_DIM) {
        float4 a = *reinterpret_cast<const float4*>(Xre + i);
        float4 b = *reinterpret_cast<const float4*>(Xim + i);
        *(uint2*)(XreB + i) = make_uint2(pk(a.x, a.y), pk(a.z, a.w));
        *(uint2*)(XimB + i) = make_uint2(pk(b.x, b.y), pk(b.z, b.w));
    }
}

// ---------------------------------------------------------------------------
// Phase 1 (r6 structure + BT-in-WRITE): coeffs[b,k] = (sum_d X*conj(B))*w[k].
// k-tile 128; KS=64; bases staged at 256B/instruction; X staged from bf16.
// WB: mirror the packed bf16 bases tile to BT[dt][k][64] INSIDE WRITE() —
// WRITE already waits on the loads (it consumes the staging registers), so
// unlike r9's LOADS-placement this does NOT break the prefetch overlap.
// ---------------------------------------------------------------------------
#define P1_STRIDE 72  // 64 d + 8 pad

template <bool XBF, bool WB>
__global__ __launch_bounds__(256, 2) void p1_coeffs(
    const float* __restrict__ XreF, const float* __restrict__ XimF,
    const __bf16* __restrict__ XreB, const __bf16* __restrict__ XimB,
    const float* __restrict__ Bre, const float* __restrict__ Bim,
    const float* __restrict__ Wre, const float* __restrict__ Wim,
    __bf16* __restrict__ BTre, __bf16* __restrict__ BTim,
    float* __restrict__ Cre, float* __restrict__ Cim)
{
    __shared__ __align__(16) __bf16 sX[2][64][P1_STRIDE];     // [re/im][b][d]
    __shared__ __align__(16) __bf16 sB[2][KTILE][P1_STRIDE];  // [re/im][k][d]

    const int ktg = blockIdx.x;       // 16 k-groups of 128  (xcd = ktg%8)
    const int dc  = blockIdx.y;       // 32 d-chunks of 1024
    const int tid  = threadIdx.x;
    const int lane = tid & 63;
    const int w    = tid >> 6;
    const int r    = lane & 15;
    const int g    = lane >> 4;

    const int kbase  = ktg * KTILE;
    const int dstart = dc * 1024;
    const int dend   = min(dstart + 1024, D_DIM);
    const int nsteps = (dend - dstart + 63) >> 6;

    const int srow = tid >> 4;          // 0..15 (+16 per j)
    const int sd   = (tid & 15) * 4;    // f32 elems 0..60
    const int rowx = tid >> 3;          // 0..31 (+32 per j)
    const int colx = (tid & 7) * 8;     // bf16 elems 0..56

    f32x4 bst[16];
    uint4 xst[4];
    f32x4 xstf[8];

    auto LOADS = [&](int s) {
        const int dg = dstart + s * 64 + sd;
        #pragma unroll
        for (int j = 0; j < 8; ++j) {
            const int row = j * 16 + srow;
            bst[j]     = ld4g(Bre + (size_t)(kbase + row) * D_DIM, dg, dend);
            bst[8 + j] = ld4g(Bim + (size_t)(kbase + row) * D_DIM, dg, dend);
        }
        if (XBF) {
            const int dgx = dstart + s * 64 + colx;
            xst[0] = ld8bf(XreB + (size_t)rowx * D_DIM,        dgx, dend);
            xst[1] = ld8bf(XreB + (size_t)(rowx + 32) * D_DIM, dgx, dend);
            xst[2] = ld8bf(XimB + (size_t)rowx * D_DIM,        dgx, dend);
            xst[3] = ld8bf(XimB + (size_t)(rowx + 32) * D_DIM, dgx, dend);
        } else {
            #pragma unroll
            for (int j = 0; j < 4; ++j) {
                const int row = j * 16 + srow;
                xstf[j]     = ld4g(XreF + (size_t)row * D_DIM, dg, dend);
                xstf[4 + j] = ld4g(XimF + (size_t)row * D_DIM, dg, dend);
            }
        }
    };

    auto WRITE = [&](int s) {
        const int dt = dc * 16 + s;     // global 64-d tile index
        #pragma unroll
        for (int j = 0; j < 8; ++j) {
            const int row = j * 16 + srow;
            const uint2 vre = make_uint2(pk(bst[j][0],     bst[j][1]),     pk(bst[j][2],     bst[j][3]));
            const uint2 vim = make_uint2(pk(bst[8 + j][0], bst[8 + j][1]), pk(bst[8 + j][2], bst[8 + j][3]));
            *(uint2*)&sB[0][row][sd] = vre;
            *(uint2*)&sB[1][row][sd] = vim;
            if (WB) {
                const size_t bo = ((size_t)dt * K_DIM + (kbase + row)) * 64 + sd;
                *(uint2*)&BTre[bo] = vre;
                *(uint2*)&BTim[bo] = vim;
            }
        }
        if (XBF) {
            *(uint4*)&sX[0][rowx][colx]      = xst[0];
            *(uint4*)&sX[0][rowx + 32][colx] = xst[1];
            *(uint4*)&sX[1][rowx][colx]      = xst[2];
            *(uint4*)&sX[1][rowx + 32][colx] = xst[3];
        } else {
            #pragma unroll
            for (int j = 0; j < 4; ++j) {
                const int row = j * 16 + srow;
                *(uint2*)&sX[0][row][sd] = make_uint2(pk(xstf[j][0],     xstf[j][1]),     pk(xstf[j][2],     xstf[j][3]));
                *(uint2*)&sX[1][row][sd] = make_uint2(pk(xstf[4 + j][0], xstf[4 + j][1]), pk(xstf[4 + j][2], xstf[4 + j][3]));
            }
        }
    };

    const int m0  = (w & 1) * 32;     // local b quadrant (32 rows)
    const int nl0 = (w >> 1) * 64;    // local k span (64 cols)

    f32x4 accRe[2][4] = {};
    f32x4 accIm[2][4] = {};

    auto COMPUTE = [&]() {
        #pragma unroll
        for (int kk = 0; kk < 2; ++kk) {
            const int dp = kk * 32 + g * 8;
            uint4 xre[2], xim[2], bre[4], bim[4];
            #pragma unroll
            for (int ms = 0; ms < 2; ++ms) {
                xre[ms] = *(const uint4*)&sX[0][m0 + ms * 16 + r][dp];
                xim[ms] = *(const uint4*)&sX[1][m0 + ms * 16 + r][dp];
            }
            #pragma unroll
            for (int ns = 0; ns < 4; ++ns) {
                bre[ns] = *(const uint4*)&sB[0][nl0 + ns * 16 + r][dp];
                bim[ns] = *(const uint4*)&sB[1][nl0 + ns * 16 + r][dp];
            }
            #pragma unroll
            for (int ms = 0; ms < 2; ++ms)
            #pragma unroll
            for (int ns = 0; ns < 4; ++ns) {
                // C_re += Xre*Bre + Xim*Bim ; C_im += Xim*Bre - Xre*Bim
                accRe[ms][ns] = mfma16(asbf(xre[ms]), asbf(bre[ns]), accRe[ms][ns]);
                accRe[ms][ns] = mfma16(asbf(xim[ms]), asbf(bim[ns]), accRe[ms][ns]);
                accIm[ms][ns] = mfma16(asbf(xim[ms]), asbf(bre[ns]), accIm[ms][ns]);
                accIm[ms][ns] = mfma16(asbf(neg4(xre[ms])), asbf(bim[ns]), accIm[ms][ns]);
            }
        }
    };

    LOADS(0); WRITE(0); __syncthreads();
    for (int s = 0; s < nsteps; ++s) {
        if (s + 1 < nsteps) LOADS(s + 1);
        COMPUTE();
        if (s + 1 < nsteps) {
            __syncthreads();   // all reads of the buffer done
            WRITE(s + 1);      // overwrite with s+1 tile (+ BT stream-out)
            __syncthreads();   // writes visible
        }
    }

    // epilogue: scale by w[k], atomic accumulate (C/D: col=lane&15, row=g*4+i)
    #pragma unroll
    for (int ms = 0; ms < 2; ++ms)
    #pragma unroll
    for (int ns = 0; ns < 4; ++ns) {
        const int kb = kbase + nl0 + ns * 16 + r;
        const float wre = Wre[kb], wim = Wim[kb];
        #pragma unroll
        for (int i = 0; i < 4; ++i) {
            const int b = m0 + ms * 16 + g * 4 + i;
            const float cre = accRe[ms][ns][i];
            const float cim = accIm[ms][ns][i];
            atomicAdd(&Cre[b * K_DIM + kb], cre * wre - cim * wim);
            atomicAdd(&Cim[b * K_DIM + kb], cre * wim + cim * wre);
        }
    }
}

// ---------------------------------------------------------------------------
// Phase 1.5: coeffs f32 -> bf16
// ---------------------------------------------------------------------------
__global__ __launch_bounds__(256) void cbf_kernel(
    const float* __restrict__ Cre, const float* __restrict__ Cim,
    __bf16* __restrict__ CreBf, __bf16* __restrict__ CimBf)
{
    const int i = blockIdx.x * 256 + threadIdx.x;
    if (i < B_DIM * K_DIM) {
        CreBf[i] = (__bf16)Cre[i];
        CimBf[i] = (__bf16)Cim[i];
    }
}

// ---------------------------------------------------------------------------
// Phase 2 (r6 structure): out[b,d] += sum_{k in half} coeffs*bases.
// BTP: read the bf16 tile-major copy BT[dt][k][64] — each 64k x 64d step
// tile is one contiguous 16 KB block per matrix pair (measured ~66 us, r9).
// Else: f32 rows (r6 fallback). 36.9 KB dbuf; grid 507 x 2 k-halves.
// ---------------------------------------------------------------------------
#define P2_STRIDE 72  // 64 k + 8 pad (144B rows, 16B aligned)

template <bool WIM, bool BTP>
__global__ __launch_bounds__(256) void p2_project(
    const float* __restrict__ Bre, const float* __restrict__ Bim,
    const __bf16* __restrict__ BTre, const __bf16* __restrict__ BTim,
    const __bf16* __restrict__ CreBf, const __bf16* __restrict__ CimBf,
    float* __restrict__ out)
{
    __shared__ __align__(16) __bf16 sT[2][2][64][P2_STRIDE];  // [buf][mat][d][k]

    const int dt = blockIdx.x;
    const int kh = blockIdx.y;        // k half: 0 -> [0,1024), 1 -> [1024,2048)
    const int d0 = dt * 64;
    const int khbase = kh * (K_DIM / 2);
    const int tid  = threadIdx.x;
    const int lane = tid & 63;
    const int w    = tid >> 6;
    const int r    = lane & 15;
    const int g    = lane >> 4;

    // staging map: thread t handles k-rows 4*(t>>4)..+3 at d = (t&15)*4
    const int kq = tid >> 4;          // 0..15
    const int ds = (tid & 15) * 4;    // 0..60

    f32x4 st[8];          // f32 path: 4 k-rows x {re, im}
    uint2 su[8];          // BT path: packed bf16 x4 per k-row

    auto LOADS = [&](int t) {
        const int k0 = khbase + t * 64;
        if (BTP) {
            #pragma unroll
            for (int j = 0; j < 4; ++j) {
                const size_t bo = ((size_t)dt * K_DIM + (k0 + kq * 4 + j)) * 64 + ds;
                su[j]     = *(const uint2*)&BTre[bo];
                su[4 + j] = *(const uint2*)&BTim[bo];
            }
        } else {
            #pragma unroll
            for (int j = 0; j < 4; ++j) {
                const size_t ro = (size_t)(k0 + kq * 4 + j) * D_DIM;
                st[j]     = ld4g(Bre + ro, d0 + ds, D_DIM);
                st[4 + j] = ld4g(Bim + ro, d0 + ds, D_DIM);
            }
        }
    };

    auto WRITE = [&](int buf) {
        if (BTP) {
            union { uint2 u; ushort h[4]; } re[4], im[4];
            #pragma unroll
            for (int j = 0; j < 4; ++j) { re[j].u = su[j]; im[j].u = su[4 + j]; }
            #pragma unroll
            for (int i = 0; i < 4; ++i) {
                *(uint2*)&sT[buf][0][ds + i][kq * 4] = make_uint2(
                    (uint32_t)re[0].h[i] | ((uint32_t)re[1].h[i] << 16),
                    (uint32_t)re[2].h[i] | ((uint32_t)re[3].h[i] << 16));
                *(uint2*)&sT[buf][1][ds + i][kq * 4] = make_uint2(
                    (uint32_t)im[0].h[i] | ((uint32_t)im[1].h[i] << 16),
                    (uint32_t)im[2].h[i] | ((uint32_t)im[3].h[i] << 16));
            }
        } else {
            #pragma unroll
            for (int i = 0; i < 4; ++i) {
                *(uint2*)&sT[buf][0][ds + i][kq * 4] =
                    make_uint2(pk(st[0][i], st[1][i]), pk(st[2][i], st[3][i]));
                *(uint2*)&sT[buf][1][ds + i][kq * 4] =
                    make_uint2(pk(st[4][i], st[5][i]), pk(st[6][i], st[7][i]));
            }
        }
    };

    const int m0  = (w & 1) * 32;     // b quadrant
    const int nl0 = (w >> 1) * 32;    // local d quadrant

    f32x4 accRe[2][2] = {};
    f32x4 accIm[2][2] = {};

    auto COMPUTE = [&](int t, int buf) {
        const int k0 = khbase + t * 64;
        uint4 aRe[2][2], aIm[2][2];
        #pragma unroll
        for (int ms = 0; ms < 2; ++ms) {
            const size_t rowo = (size_t)(m0 + ms * 16 + r) * K_DIM;
            #pragma unroll
            for (int kk = 0; kk < 2; ++kk) {
                aRe[ms][kk] = *(const uint4*)&CreBf[rowo + k0 + kk * 32 + g * 8];
                aIm[ms][kk] = *(const uint4*)&CimBf[rowo + k0 + kk * 32 + g * 8];
            }
        }
        #pragma unroll
        for (int kk = 0; kk < 2; ++kk) {
            uint4 bre[2], bim[2];
            #pragma unroll
            for (int ns = 0; ns < 2; ++ns) {
                bre[ns] = *(const uint4*)&sT[buf][0][nl0 + ns * 16 + r][kk * 32 + g * 8];
                bim[ns] = *(const uint4*)&sT[buf][1][nl0 + ns * 16 + r][kk * 32 + g * 8];
            }
            #pragma unroll
            for (int ms = 0; ms < 2; ++ms)
            #pragma unroll
            for (int ns = 0; ns < 2; ++ns) {
                // out_re += cre*Bre - cim*Bim ; out_im += cre*Bim + cim*Bre
                accRe[ms][ns] = mfma16(asbf(aRe[ms][kk]), asbf(bre[ns]), accRe[ms][ns]);
                accRe[ms][ns] = mfma16(asbf(neg4(aIm[ms][kk])), asbf(bim[ns]), accRe[ms][ns]);
                if (WIM) {
                    accIm[ms][ns] = mfma16(asbf(aRe[ms][kk]), asbf(bim[ns]), accIm[ms][ns]);
                    accIm[ms][ns] = mfma16(asbf(aIm[ms][kk]), asbf(bre[ns]), accIm[ms][ns]);
                }
            }
        }
    };

    const int NT = (K_DIM / 2) / 64;  // 16
    LOADS(0); WRITE(0); __syncthreads();
    for (int t = 0; t < NT; ++t) {
        if (t + 1 < NT) LOADS(t + 1);
        COMPUTE(t, t & 1);
        if (t + 1 < NT) WRITE((t + 1) & 1);
        __syncthreads();
    }

    #pragma unroll
    for (int ms = 0; ms < 2; ++ms)
    #pragma unroll
    for (int ns = 0; ns < 2; ++ns) {
        const int d = d0 + nl0 + ns * 16 + r;
        if (d < D_DIM) {
            #pragma unroll
            for (int i = 0; i < 4; ++i) {
                const int b = m0 + ms * 16 + g * 4 + i;
                if (!WIM) {
                    atomicAdd(&out[(size_t)b * D_DIM + d], accRe[ms][ns][i]);
                } else {
                    atomicAdd(&out[((size_t)b * D_DIM + d) * 2],     accRe[ms][ns][i]);
                    atomicAdd(&out[((size_t)b * D_DIM + d) * 2 + 1], accIm[ms][ns][i]);
                }
            }
        }
    }
}

extern "C" void kernel_launch(void* const* d_in, const int* in_sizes, int n_in,
                              void* d_out, int out_size, void* d_ws, size_t ws_size,
                              hipStream_t stream) {
    const float* Xre = (const float*)d_in[0];
    const float* Xim = (const float*)d_in[1];
    const float* Bre = (const float*)d_in[2];
    const float* Bim = (const float*)d_in[3];
    const float* Wre = (const float*)d_in[4];
    const float* Wim = (const float*)d_in[5];

    float*  Cre   = (float*)d_ws;                          // 512 KB
    float*  Cim   = Cre + B_DIM * K_DIM;                   // 512 KB
    __bf16* CreBf = (__bf16*)(Cim + B_DIM * K_DIM);        // 256 KB
    __bf16* CimBf = CreBf + B_DIM * K_DIM;                 // 256 KB
    __bf16* XreB  = CimBf + B_DIM * K_DIM;                 // 4.15 MB
    __bf16* XimB  = XreB + (size_t)B_DIM * D_DIM;          // 4.15 MB
    __bf16* BTre  = XimB + (size_t)B_DIM * D_DIM;          // 132.9 MB
    __bf16* BTim  = BTre + (size_t)NDT * K_DIM * 64;       // 132.9 MB

    const size_t needX = (size_t)2 * B_DIM * K_DIM * sizeof(float)
                       + (size_t)2 * B_DIM * K_DIM * sizeof(__bf16)
                       + (size_t)2 * B_DIM * D_DIM * sizeof(__bf16);
    const size_t needBT = needX + (size_t)2 * NDT * K_DIM * 64 * sizeof(__bf16);
    const bool xbf = ws_size >= needX;
    const bool bt  = ws_size >= needBT;

    (void)hipMemsetAsync(d_ws, 0, (size_t)2 * B_DIM * K_DIM * sizeof(float), stream);
    (void)hipMemsetAsync(d_out, 0, (size_t)out_size * sizeof(float), stream);

    dim3 g1(K_DIM / KTILE, 32);  // x = k-group (drives XCD assignment), y = d-chunk
    if (xbf) {
        xbf_kernel<<<(B_DIM * D_DIM / 4 + 255) / 256, 256, 0, stream>>>(Xre, Xim, XreB, XimB);
        if (bt) p1_coeffs<true, true><<<g1, 256, 0, stream>>>(Xre, Xim, XreB, XimB, Bre, Bim, Wre, Wim, BTre, BTim, Cre, Cim);
        else    p1_coeffs<true, false><<<g1, 256, 0, stream>>>(Xre, Xim, XreB, XimB, Bre, Bim, Wre, Wim, BTre, BTim, Cre, Cim);
    } else {
        p1_coeffs<false, false><<<g1, 256, 0, stream>>>(Xre, Xim, XreB, XimB, Bre, Bim, Wre, Wim, BTre, BTim, Cre, Cim);
    }

    cbf_kernel<<<(B_DIM * K_DIM + 255) / 256, 256, 0, stream>>>(Cre, Cim, CreBf, CimBf);

    dim3 g2(NDT, 2);
    const bool wim = (out_size == 2 * B_DIM * D_DIM);
    if (wim) {
        if (bt) p2_project<true, true><<<g2, 256, 0, stream>>>(Bre, Bim, BTre, BTim, CreBf, CimBf, (float*)d_out);
        else    p2_project<true, false><<<g2, 256, 0, stream>>>(Bre, Bim, BTre, BTim, CreBf, CimBf, (float*)d_out);
    } else {
        if (bt) p2_project<false, true><<<g2, 256, 0, stream>>>(Bre, Bim, BTre, BTim, CreBf, CimBf, (float*)d_out);
        else    p2_project<false, false><<<g2, 256, 0, stream>>>(Bre, Bim, BTre, BTim, CreBf, CimBf, (float*)d_out);
    }
}

// Round 13
// 284.952 us; speedup vs baseline: 2.2674x; 1.0212x over previous
//
#include <hip/hip_runtime.h>
#include <hip/hip_bf16.h>
#include <cstdint>
#include <cstddef>

#define B_DIM 64
#define K_DIM 2048
#define D_DIM 32400
#define KTILE 128
#define NDT   507   // number of 64-wide d-tiles (507*64 = 32448 >= 32400)

typedef __bf16 bf16x8 __attribute__((ext_vector_type(8)));
typedef float f32x4 __attribute__((ext_vector_type(4)));

union U128 { uint4 u; bf16x8 b; };

__device__ inline bf16x8 asbf(uint4 u) { U128 x; x.u = u; return x.b; }

__device__ inline uint4 neg4(uint4 u) {
    u.x ^= 0x80008000u; u.y ^= 0x80008000u; u.z ^= 0x80008000u; u.w ^= 0x80008000u;
    return u;
}

__device__ inline f32x4 mfma16(bf16x8 a, bf16x8 b, f32x4 c) {
    return __builtin_amdgcn_mfma_f32_16x16x32_bf16(a, b, c, 0, 0, 0);
}

// guarded float4 load: element index d within row pointer p, limit dlim
__device__ inline f32x4 ld4g(const float* __restrict__ p, int d, int dlim) {
    f32x4 r;
    if (d + 4 <= dlim) {
        float4 v = *reinterpret_cast<const float4*>(p + d);
        r[0] = v.x; r[1] = v.y; r[2] = v.z; r[3] = v.w;
    } else {
        #pragma unroll
        for (int j = 0; j < 4; ++j) r[j] = (d + j < dlim) ? p[d + j] : 0.0f;
    }
    return r;
}

// guarded 8x bf16 (16B) load
__device__ inline uint4 ld8bf(const __bf16* __restrict__ p, int d, int dlim) {
    if (d + 8 <= dlim) return *reinterpret_cast<const uint4*>(p + d);
    union { uint4 u; __bf16 h[8]; } x;
    #pragma unroll
    for (int j = 0; j < 8; ++j) x.h[j] = (d + j < dlim) ? p[d + j] : (__bf16)0.0f;
    return x.u;
}

// pack two floats -> dword of 2 bf16 (lo = a, hi = b)
__device__ inline uint32_t pk(float a, float b) {
    union { __bf16 h[2]; uint32_t u; } x;
    x.h[0] = (__bf16)a; x.h[1] = (__bf16)b;
    return x.u;
}

// ---------------------------------------------------------------------------
// Phase 0: X f32 -> bf16
// ---------------------------------------------------------------------------
__global__ __launch_bounds__(256) void xbf_kernel(
    const float* __restrict__ Xre, const float* __restrict__ Xim,
    __bf16* __restrict__ XreB, __bf16* __restrict__ XimB)
{
    const int i = (blockIdx.x * 256 + threadIdx.x) * 4;
    if (i < B_DIM * D_DIM) {
        float4 a = *reinterpret_cast<const float4*>(Xre + i);
        float4 b = *reinterpret_cast<const float4*>(Xim + i);
        *(uint2*)(XreB + i) = make_uint2(pk(a.x, a.y), pk(a.z, a.w));
        *(uint2*)(XimB + i) = make_uint2(pk(b.x, b.y), pk(b.z, b.w));
    }
}

// ---------------------------------------------------------------------------
// Phase 1 (r12 + combined-BT): coeffs[b,k] = (sum_d X*conj(B))*w[k].
// k-tile 128; KS=64; bases staged at 256B/instruction; X staged from bf16.
// WB: mirror packed bf16 bases tiles into ONE combined buffer
// BTc[dt][k][128]: per row, 16 groups of {re(4) 8B | im(4) 8B} -> each
// thread stores ONE uint4 (16B) per row instead of two uint2s; wave store
// = 256B contiguous. Placed in WRITE() so prefetch overlap is preserved.
// ---------------------------------------------------------------------------
#define P1_STRIDE 72  // 64 d + 8 pad

template <bool XBF, bool WB>
__global__ __launch_bounds__(256, 2) void p1_coeffs(
    const float* __restrict__ XreF, const float* __restrict__ XimF,
    const __bf16* __restrict__ XreB, const __bf16* __restrict__ XimB,
    const float* __restrict__ Bre, const float* __restrict__ Bim,
    const float* __restrict__ Wre, const float* __restrict__ Wim,
    __bf16* __restrict__ BTc,
    float* __restrict__ Cre, float* __restrict__ Cim)
{
    __shared__ __align__(16) __bf16 sX[2][64][P1_STRIDE];     // [re/im][b][d]
    __shared__ __align__(16) __bf16 sB[2][KTILE][P1_STRIDE];  // [re/im][k][d]

    const int ktg = blockIdx.x;       // 16 k-groups of 128  (xcd = ktg%8)
    const int dc  = blockIdx.y;       // 32 d-chunks of 1024
    const int tid  = threadIdx.x;
    const int lane = tid & 63;
    const int w    = tid >> 6;
    const int r    = lane & 15;
    const int g    = lane >> 4;

    const int kbase  = ktg * KTILE;
    const int dstart = dc * 1024;
    const int dend   = min(dstart + 1024, D_DIM);
    const int nsteps = (dend - dstart + 63) >> 6;

    const int srow = tid >> 4;          // 0..15 (+16 per j)
    const int sd   = (tid & 15) * 4;    // f32 elems 0..60
    const int rowx = tid >> 3;          // 0..31 (+32 per j)
    const int colx = (tid & 7) * 8;     // bf16 elems 0..56

    f32x4 bst[16];
    uint4 xst[4];
    f32x4 xstf[8];

    auto LOADS = [&](int s) {
        const int dg = dstart + s * 64 + sd;
        #pragma unroll
        for (int j = 0; j < 8; ++j) {
            const int row = j * 16 + srow;
            bst[j]     = ld4g(Bre + (size_t)(kbase + row) * D_DIM, dg, dend);
            bst[8 + j] = ld4g(Bim + (size_t)(kbase + row) * D_DIM, dg, dend);
        }
        if (XBF) {
            const int dgx = dstart + s * 64 + colx;
            xst[0] = ld8bf(XreB + (size_t)rowx * D_DIM,        dgx, dend);
            xst[1] = ld8bf(XreB + (size_t)(rowx + 32) * D_DIM, dgx, dend);
            xst[2] = ld8bf(XimB + (size_t)rowx * D_DIM,        dgx, dend);
            xst[3] = ld8bf(XimB + (size_t)(rowx + 32) * D_DIM, dgx, dend);
        } else {
            #pragma unroll
            for (int j = 0; j < 4; ++j) {
                const int row = j * 16 + srow;
                xstf[j]     = ld4g(XreF + (size_t)row * D_DIM, dg, dend);
                xstf[4 + j] = ld4g(XimF + (size_t)row * D_DIM, dg, dend);
            }
        }
    };

    auto WRITE = [&](int s) {
        const int dt = dc * 16 + s;     // global 64-d tile index
        #pragma unroll
        for (int j = 0; j < 8; ++j) {
            const int row = j * 16 + srow;
            const uint2 vre = make_uint2(pk(bst[j][0],     bst[j][1]),     pk(bst[j][2],     bst[j][3]));
            const uint2 vim = make_uint2(pk(bst[8 + j][0], bst[8 + j][1]), pk(bst[8 + j][2], bst[8 + j][3]));
            *(uint2*)&sB[0][row][sd] = vre;
            *(uint2*)&sB[1][row][sd] = vim;
            if (WB) {
                // combined row: 16 x {re 8B | im 8B}; offset in bf16 elems
                const size_t bo = ((size_t)dt * K_DIM + (kbase + row)) * 128 + sd * 2;
                *(uint4*)&BTc[bo] = make_uint4(vre.x, vre.y, vim.x, vim.y);
            }
        }
        if (XBF) {
            *(uint4*)&sX[0][rowx][colx]      = xst[0];
            *(uint4*)&sX[0][rowx + 32][colx] = xst[1];
            *(uint4*)&sX[1][rowx][colx]      = xst[2];
            *(uint4*)&sX[1][rowx + 32][colx] = xst[3];
        } else {
            #pragma unroll
            for (int j = 0; j < 4; ++j) {
                const int row = j * 16 + srow;
                *(uint2*)&sX[0][row][sd] = make_uint2(pk(xstf[j][0],     xstf[j][1]),     pk(xstf[j][2],     xstf[j][3]));
                *(uint2*)&sX[1][row][sd] = make_uint2(pk(xstf[4 + j][0], xstf[4 + j][1]), pk(xstf[4 + j][2], xstf[4 + j][3]));
            }
        }
    };

    const int m0  = (w & 1) * 32;     // local b quadrant (32 rows)
    const int nl0 = (w >> 1) * 64;    // local k span (64 cols)

    f32x4 accRe[2][4] = {};
    f32x4 accIm[2][4] = {};

    auto COMPUTE = [&]() {
        #pragma unroll
        for (int kk = 0; kk < 2; ++kk) {
            const int dp = kk * 32 + g * 8;
            uint4 xre[2], xim[2], bre[4], bim[4];
            #pragma unroll
            for (int ms = 0; ms < 2; ++ms) {
                xre[ms] = *(const uint4*)&sX[0][m0 + ms * 16 + r][dp];
                xim[ms] = *(const uint4*)&sX[1][m0 + ms * 16 + r][dp];
            }
            #pragma unroll
            for (int ns = 0; ns < 4; ++ns) {
                bre[ns] = *(const uint4*)&sB[0][nl0 + ns * 16 + r][dp];
                bim[ns] = *(const uint4*)&sB[1][nl0 + ns * 16 + r][dp];
            }
            #pragma unroll
            for (int ms = 0; ms < 2; ++ms)
            #pragma unroll
            for (int ns = 0; ns < 4; ++ns) {
                // C_re += Xre*Bre + Xim*Bim ; C_im += Xim*Bre - Xre*Bim
                accRe[ms][ns] = mfma16(asbf(xre[ms]), asbf(bre[ns]), accRe[ms][ns]);
                accRe[ms][ns] = mfma16(asbf(xim[ms]), asbf(bim[ns]), accRe[ms][ns]);
                accIm[ms][ns] = mfma16(asbf(xim[ms]), asbf(bre[ns]), accIm[ms][ns]);
                accIm[ms][ns] = mfma16(asbf(neg4(xre[ms])), asbf(bim[ns]), accIm[ms][ns]);
            }
        }
    };

    LOADS(0); WRITE(0); __syncthreads();
    for (int s = 0; s < nsteps; ++s) {
        if (s + 1 < nsteps) LOADS(s + 1);
        COMPUTE();
        if (s + 1 < nsteps) {
            __syncthreads();   // all reads of the buffer done
            WRITE(s + 1);      // overwrite with s+1 tile (+ BT stream-out)
            __syncthreads();   // writes visible
        }
    }

    // epilogue: scale by w[k], atomic accumulate (C/D: col=lane&15, row=g*4+i)
    #pragma unroll
    for (int ms = 0; ms < 2; ++ms)
    #pragma unroll
    for (int ns = 0; ns < 4; ++ns) {
        const int kb = kbase + nl0 + ns * 16 + r;
        const float wre = Wre[kb], wim = Wim[kb];
        #pragma unroll
        for (int i = 0; i < 4; ++i) {
            const int b = m0 + ms * 16 + g * 4 + i;
            const float cre = accRe[ms][ns][i];
            const float cim = accIm[ms][ns][i];
            atomicAdd(&Cre[b * K_DIM + kb], cre * wre - cim * wim);
            atomicAdd(&Cim[b * K_DIM + kb], cre * wim + cim * wre);
        }
    }
}

// ---------------------------------------------------------------------------
// Phase 1.5: coeffs f32 -> bf16 (vectorized x4)
// ---------------------------------------------------------------------------
__global__ __launch_bounds__(256) void cbf_kernel(
    const float* __restrict__ Cre, const float* __restrict__ Cim,
    __bf16* __restrict__ CreBf, __bf16* __restrict__ CimBf)
{
    const int i = (blockIdx.x * 256 + threadIdx.x) * 4;
    if (i < B_DIM * K_DIM) {
        float4 a = *reinterpret_cast<const float4*>(Cre + i);
        float4 b = *reinterpret_cast<const float4*>(Cim + i);
        *(uint2*)(CreBf + i) = make_uint2(pk(a.x, a.y), pk(a.z, a.w));
        *(uint2*)(CimBf + i) = make_uint2(pk(b.x, b.y), pk(b.z, b.w));
    }
}

// ---------------------------------------------------------------------------
// Phase 2 (r12 + combined-BT): out[b,d] += sum_{k in half} coeffs*bases.
// BTP: read BTc[dt][k][128] — one uint4 per k-row yields both re and im
// fragments; a wave instruction covers 1KB contiguous (4 x 256B rows).
// Else: f32 rows (fallback). 36.9 KB dbuf; grid 507 x 2 k-halves.
// ---------------------------------------------------------------------------
#define P2_STRIDE 72  // 64 k + 8 pad (144B rows, 16B aligned)

template <bool WIM, bool BTP>
__global__ __launch_bounds__(256) void p2_project(
    const float* __restrict__ Bre, const float* __restrict__ Bim,
    const __bf16* __restrict__ BTc,
    const __bf16* __restrict__ CreBf, const __bf16* __restrict__ CimBf,
    float* __restrict__ out)
{
    __shared__ __align__(16) __bf16 sT[2][2][64][P2_STRIDE];  // [buf][mat][d][k]

    const int dt = blockIdx.x;
    const int kh = blockIdx.y;        // k half: 0 -> [0,1024), 1 -> [1024,2048)
    const int d0 = dt * 64;
    const int khbase = kh * (K_DIM / 2);
    const int tid  = threadIdx.x;
    const int lane = tid & 63;
    const int w    = tid >> 6;
    const int r    = lane & 15;
    const int g    = lane >> 4;

    // staging map: thread t handles k-rows 4*(t>>4)..+3 at d = (t&15)*4
    const int kq = tid >> 4;          // 0..15
    const int ds = (tid & 15) * 4;    // 0..60

    f32x4 st[8];          // f32 path: 4 k-rows x {re, im}
    uint4 su[4];          // BT path: {re 8B | im 8B} per k-row

    auto LOADS = [&](int t) {
        const int k0 = khbase + t * 64;
        if (BTP) {
            #pragma unroll
            for (int j = 0; j < 4; ++j) {
                const size_t bo = ((size_t)dt * K_DIM + (k0 + kq * 4 + j)) * 128 + ds * 2;
                su[j] = *(const uint4*)&BTc[bo];
            }
        } else {
            #pragma unroll
            for (int j = 0; j < 4; ++j) {
                const size_t ro = (size_t)(k0 + kq * 4 + j) * D_DIM;
                st[j]     = ld4g(Bre + ro, d0 + ds, D_DIM);
                st[4 + j] = ld4g(Bim + ro, d0 + ds, D_DIM);
            }
        }
    };

    auto WRITE = [&](int buf) {
        if (BTP) {
            union { uint2 u; ushort h[4]; } re[4], im[4];
            #pragma unroll
            for (int j = 0; j < 4; ++j) {
                re[j].u = make_uint2(su[j].x, su[j].y);
                im[j].u = make_uint2(su[j].z, su[j].w);
            }
            #pragma unroll
            for (int i = 0; i < 4; ++i) {
                *(uint2*)&sT[buf][0][ds + i][kq * 4] = make_uint2(
                    (uint32_t)re[0].h[i] | ((uint32_t)re[1].h[i] << 16),
                    (uint32_t)re[2].h[i] | ((uint32_t)re[3].h[i] << 16));
                *(uint2*)&sT[buf][1][ds + i][kq * 4] = make_uint2(
                    (uint32_t)im[0].h[i] | ((uint32_t)im[1].h[i] << 16),
                    (uint32_t)im[2].h[i] | ((uint32_t)im[3].h[i] << 16));
            }
        } else {
            #pragma unroll
            for (int i = 0; i < 4; ++i) {
                *(uint2*)&sT[buf][0][ds + i][kq * 4] =
                    make_uint2(pk(st[0][i], st[1][i]), pk(st[2][i], st[3][i]));
                *(uint2*)&sT[buf][1][ds + i][kq * 4] =
                    make_uint2(pk(st[4][i], st[5][i]), pk(st[6][i], st[7][i]));
            }
        }
    };

    const int m0  = (w & 1) * 32;     // b quadrant
    const int nl0 = (w >> 1) * 32;    // local d quadrant

    f32x4 accRe[2][2] = {};
    f32x4 accIm[2][2] = {};

    auto COMPUTE = [&](int t, int buf) {
        const int k0 = khbase + t * 64;
        uint4 aRe[2][2], aIm[2][2];
        #pragma unroll
        for (int ms = 0; ms < 2; ++ms) {
            const size_t rowo = (size_t)(m0 + ms * 16 + r) * K_DIM;
            #pragma unroll
            for (int kk = 0; kk < 2; ++kk) {
                aRe[ms][kk] = *(const uint4*)&CreBf[rowo + k0 + kk * 32 + g * 8];
                aIm[ms][kk] = *(const uint4*)&CimBf[rowo + k0 + kk * 32 + g * 8];
            }
        }
        #pragma unroll
        for (int kk = 0; kk < 2; ++kk) {
            uint4 bre[2], bim[2];
            #pragma unroll
            for (int ns = 0; ns < 2; ++ns) {
                bre[ns] = *(const uint4*)&sT[buf][0][nl0 + ns * 16 + r][kk * 32 + g * 8];
                bim[ns] = *(const uint4*)&sT[buf][1][nl0 + ns * 16 + r][kk * 32 + g * 8];
            }
            #pragma unroll
            for (int ms = 0; ms < 2; ++ms)
            #pragma unroll
            for (int ns = 0; ns < 2; ++ns) {
                // out_re += cre*Bre - cim*Bim ; out_im += cre*Bim + cim*Bre
                accRe[ms][ns] = mfma16(asbf(aRe[ms][kk]), asbf(bre[ns]), accRe[ms][ns]);
                accRe[ms][ns] = mfma16(asbf(neg4(aIm[ms][kk])), asbf(bim[ns]), accRe[ms][ns]);
                if (WIM) {
                    accIm[ms][ns] = mfma16(asbf(aRe[ms][kk]), asbf(bim[ns]), accIm[ms][ns]);
                    accIm[ms][ns] = mfma16(asbf(aIm[ms][kk]), asbf(bre[ns]), accIm[ms][ns]);
                }
            }
        }
    };

    const int NT = (K_DIM / 2) / 64;  // 16
    LOADS(0); WRITE(0); __syncthreads();
    for (int t = 0; t < NT; ++t) {
        if (t + 1 < NT) LOADS(t + 1);
        COMPUTE(t, t & 1);
        if (t + 1 < NT) WRITE((t + 1) & 1);
        __syncthreads();
    }

    #pragma unroll
    for (int ms = 0; ms < 2; ++ms)
    #pragma unroll
    for (int ns = 0; ns < 2; ++ns) {
        const int d = d0 + nl0 + ns * 16 + r;
        if (d < D_DIM) {
            #pragma unroll
            for (int i = 0; i < 4; ++i) {
                const int b = m0 + ms * 16 + g * 4 + i;
                if (!WIM) {
                    atomicAdd(&out[(size_t)b * D_DIM + d], accRe[ms][ns][i]);
                } else {
                    atomicAdd(&out[((size_t)b * D_DIM + d) * 2],     accRe[ms][ns][i]);
                    atomicAdd(&out[((size_t)b * D_DIM + d) * 2 + 1], accIm[ms][ns][i]);
                }
            }
        }
    }
}

extern "C" void kernel_launch(void* const* d_in, const int* in_sizes, int n_in,
                              void* d_out, int out_size, void* d_ws, size_t ws_size,
                              hipStream_t stream) {
    const float* Xre = (const float*)d_in[0];
    const float* Xim = (const float*)d_in[1];
    const float* Bre = (const float*)d_in[2];
    const float* Bim = (const float*)d_in[3];
    const float* Wre = (const float*)d_in[4];
    const float* Wim = (const float*)d_in[5];

    float*  Cre   = (float*)d_ws;                          // 512 KB
    float*  Cim   = Cre + B_DIM * K_DIM;                   // 512 KB
    __bf16* CreBf = (__bf16*)(Cim + B_DIM * K_DIM);        // 256 KB
    __bf16* CimBf = CreBf + B_DIM * K_DIM;                 // 256 KB
    __bf16* XreB  = CimBf + B_DIM * K_DIM;                 // 4.15 MB
    __bf16* XimB  = XreB + (size_t)B_DIM * D_DIM;          // 4.15 MB
    __bf16* BTc   = XimB + (size_t)B_DIM * D_DIM;          // 265.8 MB (re|im combined)

    const size_t needX = (size_t)2 * B_DIM * K_DIM * sizeof(float)
                       + (size_t)2 * B_DIM * K_DIM * sizeof(__bf16)
                       + (size_t)2 * B_DIM * D_DIM * sizeof(__bf16);
    const size_t needBT = needX + (size_t)NDT * K_DIM * 128 * sizeof(__bf16);
    const bool xbf = ws_size >= needX;
    const bool bt  = ws_size >= needBT;

    (void)hipMemsetAsync(d_ws, 0, (size_t)2 * B_DIM * K_DIM * sizeof(float), stream);
    (void)hipMemsetAsync(d_out, 0, (size_t)out_size * sizeof(float), stream);

    dim3 g1(K_DIM / KTILE, 32);  // x = k-group (drives XCD assignment), y = d-chunk
    if (xbf) {
        xbf_kernel<<<(B_DIM * D_DIM / 4 + 255) / 256, 256, 0, stream>>>(Xre, Xim, XreB, XimB);
        if (bt) p1_coeffs<true, true><<<g1, 256, 0, stream>>>(Xre, Xim, XreB, XimB, Bre, Bim, Wre, Wim, BTc, Cre, Cim);
        else    p1_coeffs<true, false><<<g1, 256, 0, stream>>>(Xre, Xim, XreB, XimB, Bre, Bim, Wre, Wim, BTc, Cre, Cim);
    } else {
        p1_coeffs<false, false><<<g1, 256, 0, stream>>>(Xre, Xim, XreB, XimB, Bre, Bim, Wre, Wim, BTc, Cre, Cim);
    }

    cbf_kernel<<<(B_DIM * K_DIM / 4 + 255) / 256, 256, 0, stream>>>(Cre, Cim, CreBf, CimBf);

    dim3 g2(NDT, 2);
    const bool wim = (out_size == 2 * B_DIM * D_DIM);
    if (wim) {
        if (bt) p2_project<true, true><<<g2, 256, 0, stream>>>(Bre, Bim, BTc, CreBf, CimBf, (float*)d_out);
        else    p2_project<true, false><<<g2, 256, 0, stream>>>(Bre, Bim, BTc, CreBf, CimBf, (float*)d_out);
    } else {
        if (bt) p2_project<false, true><<<g2, 256, 0, stream>>>(Bre, Bim, BTc, CreBf, CimBf, (float*)d_out);
        else    p2_project<false, false><<<g2, 256, 0, stream>>>(Bre, Bim, BTc, CreBf, CimBf, (float*)d_out);
    }
}